// Round 4
// baseline (98.879 us; speedup 1.0000x reference)
//
#include <hip/hip_runtime.h>

typedef __attribute__((ext_vector_type(4))) float  f32x4;
typedef __attribute__((ext_vector_type(8))) __bf16 bf16x8;

// Chaining permutation. D-position q = mf*16 + g4*4 + r  (m = h index in D layout)
// B-position p = kk*32 + g4*8 + j                         (k = h index in B layout)
// Free register chaining: B_next[kk][j] = relu(acc[(kk<<1)|(j>>2)][j&3]) requires
// weight COLUMNS permuted by P = Q^{-1}:
// P(q) = (q>>5)*32 + ((q>>2)&3)*8 + ((q>>4)&1)*4 + (q&3).
__device__ __forceinline__ int Pq(int q) {
  return ((q >> 5) << 5) + (((q >> 2) & 3) << 3) + (((q >> 4) & 1) << 2) + (q & 3);
}

// ---------------- setup: weights -> A-fragment order, columns permuted by P ----------
__global__ void reformat_w(const float* __restrict__ h_wh,
                           const float* __restrict__ g_w1,
                           const float* __restrict__ g_wh,
                           __bf16* __restrict__ wsH,   // [2*64][4096]
                           __bf16* __restrict__ wsG)   // [3][4096]
{
  int i = blockIdx.x * 256 + threadIdx.x;
  int j = i & 7, lane = (i >> 3) & 63, f = (i >> 9) & 7;
  int c = lane & 15, g4 = lane >> 4, mf = f >> 1, kk = f & 1;
  int krow = (kk << 5) + (g4 << 3) + j;
  int mcol = Pq((mf << 4) + c);
  if (i < 524288) {                       // h: 2 layers * 64 heads * 4096
    int ld = i >> 12;
    wsH[i] = (__bf16)h_wh[(ld << 12) + (krow << 6) + mcol];
  } else if (i < 536576) {                // g: 3 matrices * 4096
    int t = i - 524288;
    int lg = t >> 12;
    const float* W = (lg == 0) ? g_w1 : g_wh + ((lg - 1) << 12);
    wsG[t] = (__bf16)W[(krow << 6) + mcol];
  }
}

// ---------------- setup: transpose x[:,64:] -> xT[d][batch] (both sides coalesced) ----
__global__ void transpose_x(const float* __restrict__ x, float* __restrict__ xT, int Btot) {
  __shared__ float t[64][65];
  const int r0 = blockIdx.x << 6;
  const int tid = threadIdx.x;
  #pragma unroll
  for (int i = 0; i < 4; ++i) {
    int r = (i << 4) + (tid >> 4), c4 = (tid & 15) << 2;
    float4 v = *(const float4*)&x[(size_t)(r0 + r) * 128 + 64 + c4];
    t[r][c4] = v.x; t[r][c4 + 1] = v.y; t[r][c4 + 2] = v.z; t[r][c4 + 3] = v.w;
  }
  __syncthreads();
  #pragma unroll
  for (int i = 0; i < 4; ++i) {
    int k = (i << 4) + (tid >> 4), r4 = (tid & 15) << 2;
    float4 v = { t[r4][k], t[r4 + 1][k], t[r4 + 2][k], t[r4 + 3][k] };
    *(float4*)&xT[(size_t)k * Btot + r0 + r4] = v;
  }
}

// ---------------- epilogue merge: hT[d][batch] -> out[batch][d] (full lines) ---------
__global__ void merge_h(const float* __restrict__ hT, float* __restrict__ out, int Btot) {
  __shared__ float t[64][65];
  const int b0 = blockIdx.x << 6;
  const int tid = threadIdx.x;
  #pragma unroll
  for (int i = 0; i < 4; ++i) {
    int dd = (i << 4) + (tid >> 4), c4 = (tid & 15) << 2;
    float4 v = *(const float4*)&hT[(size_t)dd * Btot + b0 + c4];
    t[dd][c4] = v.x; t[dd][c4 + 1] = v.y; t[dd][c4 + 2] = v.z; t[dd][c4 + 3] = v.w;
  }
  __syncthreads();
  #pragma unroll
  for (int i = 0; i < 4; ++i) {
    int b = (i << 4) + (tid >> 4), d4 = (tid & 15) << 2;
    float4 v = { t[d4][b], t[d4 + 1][b], t[d4 + 2][b], t[d4 + 3][b] };
    *(float4*)&out[(size_t)(b0 + b) * 64 + d4] = v;
  }
}

// One MFMA layer: acc = A*B + bias; optionally rebuild B-frags from acc (relu+cvt,
// pure register renaming thanks to the P-permuted weights).
__device__ __forceinline__ void layer(const __bf16* __restrict__ wf,
                                      const float* __restrict__ bias,
                                      int lane, int g4, bool rebuild,
                                      f32x4 (&acc)[4][4], bf16x8 (&bfr)[4][2])
{
  bf16x8 aw0[4], aw1[4];
  #pragma unroll
  for (int mf = 0; mf < 4; ++mf) {
    aw0[mf] = *(const bf16x8*)&wf[((mf << 1) << 9) + (lane << 3)];
    aw1[mf] = *(const bf16x8*)&wf[(((mf << 1) | 1) << 9) + (lane << 3)];
  }
  f32x4 bv[4];
  #pragma unroll
  for (int mf = 0; mf < 4; ++mf)   // bias at D-pos q: bias[P(q)], contiguous x4
    bv[mf] = *(const f32x4*)&bias[((mf >> 1) << 5) + (g4 << 3) + ((mf & 1) << 2)];
  #pragma unroll
  for (int mf = 0; mf < 4; ++mf)
    #pragma unroll
    for (int nf = 0; nf < 4; ++nf)
      acc[mf][nf] = __builtin_amdgcn_mfma_f32_16x16x32_bf16(aw0[mf], bfr[nf][0], bv[mf], 0, 0, 0);
  #pragma unroll
  for (int mf = 0; mf < 4; ++mf)
    #pragma unroll
    for (int nf = 0; nf < 4; ++nf)
      acc[mf][nf] = __builtin_amdgcn_mfma_f32_16x16x32_bf16(aw1[mf], bfr[nf][1], acc[mf][nf], 0, 0, 0);
  if (rebuild) {
    #pragma unroll
    for (int nf = 0; nf < 4; ++nf)
      #pragma unroll
      for (int kk = 0; kk < 2; ++kk) {
        bf16x8 v;
        #pragma unroll
        for (int e = 0; e < 8; ++e)
          v[e] = (__bf16)fmaxf(acc[(kk << 1) | (e >> 2)][nf][e & 3], 0.f);
        bfr[nf][kk] = v;
      }
  }
}

__global__ __launch_bounds__(256, 4) void fused_nn(
    const float* __restrict__ x,
    const float* __restrict__ h_w1, const float* __restrict__ h_b1,
    const float* __restrict__ h_bh,
    const float* __restrict__ h_wo, const float* __restrict__ h_bo,
    const float* __restrict__ g_b1, const float* __restrict__ g_bh,
    const float* __restrict__ g_wo, const float* __restrict__ g_bo,
    const __bf16* __restrict__ wsH, const __bf16* __restrict__ wsG,
    const float* __restrict__ xT, float* __restrict__ hT,
    float* __restrict__ out, int Btot, int nwg)
{
  const int tid  = threadIdx.x;
  const int lane = tid & 63;
  const int wid  = tid >> 6;
  const int c    = lane & 15;
  const int g4   = lane >> 4;

  // XCD-bijective swizzle (nwg % 8 == 0): each XCD gets a contiguous tile range.
  const int bid0 = blockIdx.x;
  const int bid  = (bid0 & 7) * (nwg >> 3) + (bid0 >> 3);
  const int tile = bid / 65;
  const int sub  = bid - tile * 65;
  const bool is_h = (sub < 64);
  const int d    = sub & 63;
  const int nb   = (tile << 8) + (wid << 6);   // wave's 64-batch base

  f32x4  acc[4][4];
  bf16x8 bfr[4][2];

  if (is_h) {
    // ---- h1 = relu(s * w1 + b1), built directly as B-fragments ----
    const float* w1p = h_w1 + (d << 6);
    const float* b1p = h_b1 + (d << 6);
    f32x4 w1v[2][2], b1v[2][2];
    #pragma unroll
    for (int kk = 0; kk < 2; ++kk)
      #pragma unroll
      for (int h = 0; h < 2; ++h) {
        int off = (kk << 5) + (g4 << 3) + (h << 2);
        w1v[kk][h] = *(const f32x4*)&w1p[off];
        b1v[kk][h] = *(const f32x4*)&b1p[off];
      }
    #pragma unroll
    for (int nf = 0; nf < 4; ++nf) {
      int batch = nb + (nf << 4) + c;
      float s = xT ? xT[(size_t)d * Btot + batch]
                   : x[(size_t)batch * 128 + 64 + d];
      #pragma unroll
      for (int kk = 0; kk < 2; ++kk) {
        bf16x8 v;
        #pragma unroll
        for (int h = 0; h < 2; ++h)
          #pragma unroll
          for (int r = 0; r < 4; ++r)
            v[(h << 2) + r] = (__bf16)fmaxf(fmaf(s, w1v[kk][h][r], b1v[kk][h][r]), 0.f);
        bfr[nf][kk] = v;
      }
    }
    layer(wsH + (d << 12),        h_bh + (d << 6),        lane, g4, true,  acc, bfr);
    layer(wsH + ((64 + d) << 12), h_bh + ((64 + d) << 6), lane, g4, false, acc, bfr);
  } else {
    // ---- g layer-1 input: x[:, :64] as B-fragments ----
    #pragma unroll
    for (int nf = 0; nf < 4; ++nf) {
      const float* xr = x + (size_t)(nb + (nf << 4) + c) * 128;
      #pragma unroll
      for (int kk = 0; kk < 2; ++kk) {
        f32x4 v0 = *(const f32x4*)&xr[(kk << 5) + (g4 << 3)];
        f32x4 v1 = *(const f32x4*)&xr[(kk << 5) + (g4 << 3) + 4];
        bf16x8 v;
        #pragma unroll
        for (int r = 0; r < 4; ++r) { v[r] = (__bf16)v0[r]; v[4 + r] = (__bf16)v1[r]; }
        bfr[nf][kk] = v;
      }
    }
    layer(wsG,        g_b1,      lane, g4, true,  acc, bfr);
    layer(wsG + 4096, g_bh,      lane, g4, true,  acc, bfr);
    layer(wsG + 8192, g_bh + 64, lane, g4, false, acc, bfr);
  }

  // ---- epilogue: relu -> dot(wo[P(q)]) -> reduce over g4 groups ----
  const float* wo = is_h ? h_wo + (d << 6) : g_wo;
  const float  ob = is_h ? h_bo[d] : g_bo[0];
  f32x4 wv[4];
  #pragma unroll
  for (int mf = 0; mf < 4; ++mf)
    wv[mf] = *(const f32x4*)&wo[((mf >> 1) << 5) + (g4 << 3) + ((mf & 1) << 2)];
  float p[4] = {0.f, 0.f, 0.f, 0.f};
  #pragma unroll
  for (int mf = 0; mf < 4; ++mf)
    #pragma unroll
    for (int nf = 0; nf < 4; ++nf)
      #pragma unroll
      for (int r = 0; r < 4; ++r)
        p[nf] += fmaxf(acc[mf][nf][r], 0.f) * wv[mf][r];
  #pragma unroll
  for (int nf = 0; nf < 4; ++nf) {
    p[nf] += __shfl_xor(p[nf], 16);
    p[nf] += __shfl_xor(p[nf], 32);
  }
  float sel = (g4 == 0) ? p[0] : (g4 == 1) ? p[1] : (g4 == 2) ? p[2] : p[3];
  int batch = nb + lane;
  if (is_h) {
    if (hT) hT[(size_t)d * Btot + batch] = sel + ob;   // coalesced; merged later
    else    out[((size_t)batch << 6) + d] = sel + ob;  // fallback (partial-line)
  } else {
    out[((size_t)Btot << 6) + batch] = sel + ob;       // coalesced
  }
}

extern "C" void kernel_launch(void* const* d_in, const int* in_sizes, int n_in,
                              void* d_out, int out_size, void* d_ws, size_t ws_size,
                              hipStream_t stream) {
  const float* x    = (const float*)d_in[0];
  const float* h_w1 = (const float*)d_in[1];
  const float* h_b1 = (const float*)d_in[2];
  const float* h_wh = (const float*)d_in[3];
  const float* h_bh = (const float*)d_in[4];
  const float* h_wo = (const float*)d_in[5];
  const float* h_bo = (const float*)d_in[6];
  const float* g_w1 = (const float*)d_in[7];
  const float* g_b1 = (const float*)d_in[8];
  const float* g_wh = (const float*)d_in[9];
  const float* g_bh = (const float*)d_in[10];
  const float* g_wo = (const float*)d_in[11];
  const float* g_bo = (const float*)d_in[12];

  const int Btot   = in_sizes[0] / 128;   // 32768
  const int nTiles = Btot >> 8;           // 128
  const int nwg    = nTiles * 65;         // 8320, %8 == 0

  char* p = (char*)d_ws;
  __bf16* wsH = (__bf16*)p;                                   // 1 MB
  __bf16* wsG = (__bf16*)(p + (size_t)2 * 64 * 4096 * 2);     // 24 KB
  size_t base = (size_t)2 * 64 * 4096 * 2 + 3 * 4096 * 2;     // 1073152 B (16-aligned)
  float* xT = nullptr;
  float* hT = nullptr;
  if (ws_size >= base + 2 * (size_t)Btot * 64 * sizeof(float)) {
    xT = (float*)(p + base);
    hT = xT + (size_t)Btot * 64;
  }

  hipLaunchKernelGGL(reformat_w, dim3(2096), dim3(256), 0, stream,
                     h_wh, g_w1, g_wh, wsH, wsG);
  if (xT)
    hipLaunchKernelGGL(transpose_x, dim3(Btot >> 6), dim3(256), 0, stream, x, xT, Btot);

  hipLaunchKernelGGL(fused_nn, dim3(nwg), dim3(256), 0, stream,
                     x, h_w1, h_b1, h_bh, h_wo, h_bo,
                     g_b1, g_bh, g_wo, g_bo,
                     (const __bf16*)wsH, (const __bf16*)wsG,
                     (const float*)xT, hT,
                     (float*)d_out, Btot, nwg);

  if (hT)
    hipLaunchKernelGGL(merge_h, dim3(Btot >> 6), dim3(256), 0, stream,
                       (const float*)hT, (float*)d_out, Btot);
}